// Round 6
// baseline (379.382 us; speedup 1.0000x reference)
//
#include <hip/hip_runtime.h>

// Problem constants
#define B_  16
#define T_  12
#define N_  1000
#define F_  64
#define KC  3
#define O_  64
#define NP  1024            // padded N (both i and j dims)
#define KP  (KC * NP)       // 3072 combined contraction length per b
#define CC  (T_ * O_)       // 768 output columns per b

typedef __bf16 bf16x8 __attribute__((ext_vector_type(8)));
typedef float  f32x4  __attribute__((ext_vector_type(4)));

__device__ __forceinline__ unsigned short f2bf(float f) {
  __bf16 h = (__bf16)f;                      // RNE convert
  return __builtin_bit_cast(unsigned short, h);
}

// async global->LDS, 16B per lane. LDS dest = wave-uniform base + lane*16.
__device__ __forceinline__ void gl_lds16(const void* g, void* l) {
  __builtin_amdgcn_global_load_lds(
      (const __attribute__((address_space(1))) unsigned int*)g,
      (__attribute__((address_space(3))) unsigned int*)l,
      16, 0, 0);
}

// ---------------------------------------------------------------------------
// Stage 1: ASt[b][ip][k][jp] = bf16(cheb[k,j,i] * SAtt[b,j,i]), zero-padded.
// b-batched 8x: cheb tile preloaded into registers, SAtt streamed per b.
// (round-3 version, FROZEN for attribution)
// grid (i-tile, j-tile, b-group) = (16,16,2), 256 threads.
// ---------------------------------------------------------------------------
__global__ __launch_bounds__(256) void k_build_as(
    const float* __restrict__ SAtt, const float* __restrict__ cheb,
    unsigned short* __restrict__ ASt) {
  __shared__ unsigned short prod[KC][64][66];   // 66 -> 132B rows (4B aligned)
  const int tid = threadIdx.x;
  const int ib = blockIdx.x * 64, jb = blockIdx.y * 64;

  const int ii4 = (tid & 15) * 4, jr = tid >> 4;
  const int gi = ib + ii4;                      // N_%4==0: f4 never straddles
  const bool iok = gi < N_;

  float4 ch[4][KC];
  int gjc[4];
  bool okm[4];
#pragma unroll
  for (int p = 0; p < 4; ++p) {
    const int gj = jb + p * 16 + jr;
    gjc[p] = gj < N_ ? gj : N_ - 1;
    okm[p] = iok && (gj < N_);
#pragma unroll
    for (int k = 0; k < KC; ++k) {
      ch[p][k] = make_float4(0.f, 0.f, 0.f, 0.f);
      if (iok)
        ch[p][k] = *(const float4*)&cheb[((size_t)k * N_ + gjc[p]) * N_ + gi];
    }
  }

  const int j8 = (tid & 7) * 8, i0 = tid >> 3;

  for (int bb = 0; bb < 8; ++bb) {
    const int b = blockIdx.z * 8 + bb;
    const float* sb = SAtt + (size_t)b * N_ * N_;
    if (bb) __syncthreads();      // protect prod from prior transpose readers
#pragma unroll
    for (int p = 0; p < 4; ++p) {
      const int jj = p * 16 + jr;
      float4 s4 = make_float4(0.f, 0.f, 0.f, 0.f);
      if (iok) s4 = *(const float4*)&sb[(size_t)gjc[p] * N_ + gi];
#pragma unroll
      for (int k = 0; k < KC; ++k) {
        ushort2 lo, hi;
        lo.x = okm[p] ? f2bf(ch[p][k].x * s4.x) : (unsigned short)0;
        lo.y = okm[p] ? f2bf(ch[p][k].y * s4.y) : (unsigned short)0;
        hi.x = okm[p] ? f2bf(ch[p][k].z * s4.z) : (unsigned short)0;
        hi.y = okm[p] ? f2bf(ch[p][k].w * s4.w) : (unsigned short)0;
        *(ushort2*)&prod[k][jj][ii4]     = lo;
        *(ushort2*)&prod[k][jj][ii4 + 2] = hi;
      }
    }
    __syncthreads();
#pragma unroll
    for (int pp = 0; pp < 2; ++pp) {
      const int iw = pp * 32 + i0;
#pragma unroll
      for (int k = 0; k < KC; ++k) {
        unsigned short v[8];
#pragma unroll
        for (int m = 0; m < 8; ++m) v[m] = prod[k][j8 + m][iw];
        *(uint4*)&ASt[((size_t)(b * NP + ib + iw) * KC + k) * NP + jb + j8] =
            *(uint4*)v;
      }
    }
  }
}

// ---------------------------------------------------------------------------
// Stage 2+3 fused: per-b GEMM C[i,c] = sum_{k,j} ASt[b][i][(k,j)] * Y[c][(k,j)]
// with Y built ON THE FLY per K-tile (Yt tensor eliminated):
//   Y[c=(t,o)][j] = sum_f x[b,t,j,f] * Theta[k,f,o]
// y-MFMA orientation mfma(A=x[j,f], B=Theta^T[o,f]) -> D[j,o]: each lane's 4
// acc values are 4 CONSECUTIVE j -> single ds_write_b64 straight into Bl's
// chunk-XOR layout (write phys chunk = logical^(crow&7) == read side's
// quad^(lr&7)^ks*4). Theta^T staged once per block. K-loop is j-tile-major so
// the x-slab (2t x 64j x 64f) is staged once per j-tile, reused for 3 k's.
// 128x128 tile, 4 waves x (64x64), BK=64, gl_lds A-staging, XCD swizzle.
// LDS: Al 16K + Bl 16K + xs 16K + thl 27.7K = 75.7 KB -> 2 blocks/CU.
// ---------------------------------------------------------------------------
__global__ __launch_bounds__(256, 2) void k_gemm(
    const unsigned short* __restrict__ ASt, const float* __restrict__ x,
    const float* __restrict__ Theta, float* __restrict__ out) {
  __shared__ unsigned short Al[128 * 64];     // A tile [row][chunk-swizzled]
  __shared__ unsigned short Bl[128 * 64];     // Y tile, same layout
  __shared__ unsigned short xs[128 * 64];     // x slab [tt*64+j][f-chunk swz]
  __shared__ unsigned short thl[KC][64][72];  // Theta^T [k][o][f], padded

  const int tid = threadIdx.x;
  // block swizzle: bid%8 -> XCD; 2 b's per XCD
  const int bid = blockIdx.x;
  const int xcd = bid & 7, s = bid >> 3;          // s = 0..95
  const int b = xcd * 2 + (s / 48);
  const int r48 = s % 48;
  const int ib = (r48 / 6) * 128, cb = (r48 % 6) * 128;
  const int t0 = cb >> 6;                          // block covers t0, t0+1
  const int bt0 = b * T_ + t0;

  const unsigned short* Abase = ASt + ((size_t)b * NP + ib) * KP;
  const int w = tid >> 6, l = tid & 63, quad = l >> 4, lr = l & 15;
  const int wr = w & 1, wc = w >> 1;
  const int lrow = l >> 3, lchunk = l & 7;
  const int src_chunk = lchunk ^ lrow;            // XOR swizzle (staging side)
  const int p0 = quad ^ (lr & 7);                 // phys chunk, ks=0 (read side)
  const int ytt = w & 1, yjh = w >> 1;            // y-build wave role: t, j-half

  // prologue: Theta -> thl (transposed), float4 loads along o
#pragma unroll
  for (int it = 0; it < 12; ++it) {
    const int e = (tid + it * 256) * 4;           // element index, mult of 4
    const int k = e >> 12, f = (e >> 6) & 63, o0 = e & 63;
    const float4 v = *(const float4*)&Theta[e];
    thl[k][o0 + 0][f] = f2bf(v.x);
    thl[k][o0 + 1][f] = f2bf(v.y);
    thl[k][o0 + 2][f] = f2bf(v.z);
    thl[k][o0 + 3][f] = f2bf(v.w);
  }

  f32x4 acc[4][4];
#pragma unroll
  for (int mi = 0; mi < 4; ++mi)
#pragma unroll
    for (int ci = 0; ci < 4; ++ci)
      acc[mi][ci] = (f32x4){0.f, 0.f, 0.f, 0.f};

#pragma unroll 1
  for (int jt = 0; jt < 16; ++jt) {
    // stage x-slab for this j-tile: 2t x 64j x 64f fp32 -> bf16, swizzled.
    // Safe without a leading barrier: all xs readers (y-MFMA) are upstream of
    // the previous inner iteration's mid-phase __syncthreads.
    const int j0 = jt * 64;
#pragma unroll
    for (int p = 0; p < 8; ++p) {
      const int idx = tid + p * 256;              // 0..2047 float4
      const int f4 = idx & 15, j = (idx >> 4) & 63, tt = idx >> 10;
      const int jg = j0 + j;
      float4 v = make_float4(0.f, 0.f, 0.f, 0.f);
      if (jg < N_)
        v = *(const float4*)&x[((size_t)(bt0 + tt) * N_ + jg) * F_ + f4 * 4];
      ushort4 u;
      u.x = f2bf(v.x); u.y = f2bf(v.y); u.z = f2bf(v.z); u.w = f2bf(v.w);
      const int rr = tt * 64 + j;
      const int off = rr * 64 + (((f4 >> 1) ^ (rr & 7)) * 8) + (f4 & 1) * 4;
      *(ushort4*)&xs[off] = u;
    }

#pragma unroll 1
    for (int k = 0; k < KC; ++k) {
      __syncthreads();            // prev main-MFMA done (Al/Bl reusable);
                                  // xs writes visible for k=0 (wave drains)
      const int koff = k * NP + j0;
      // A staging (async, drains at next barrier)
#pragma unroll
      for (int s4 = 0; s4 < 4; ++s4) {
        const int row = w * 32 + s4 * 8;          // wave-uniform LDS base row
        gl_lds16(Abase + (size_t)(row + lrow) * KP + koff + src_chunk * 8,
                 &Al[row * 64]);
      }
      // y-build: D[j,o] = x[j,f] . Theta^T[o,f], per wave a 32j x 64o slab
      f32x4 yac[2][4];
#pragma unroll
      for (int j2 = 0; j2 < 2; ++j2)
#pragma unroll
        for (int ot = 0; ot < 4; ++ot)
          yac[j2][ot] = (f32x4){0.f, 0.f, 0.f, 0.f};
#pragma unroll
      for (int ks = 0; ks < 2; ++ks) {
        bf16x8 xa[2], tb[4];
#pragma unroll
        for (int j2 = 0; j2 < 2; ++j2) {
          const int rr = ytt * 64 + yjh * 32 + j2 * 16 + lr;
          xa[j2] = *(const bf16x8*)
              &xs[rr * 64 + (((ks * 4 + quad) ^ (rr & 7)) * 8)];
        }
#pragma unroll
        for (int ot = 0; ot < 4; ++ot)
          tb[ot] = *(const bf16x8*)&thl[k][ot * 16 + lr][ks * 32 + quad * 8];
#pragma unroll
        for (int j2 = 0; j2 < 2; ++j2)
#pragma unroll
          for (int ot = 0; ot < 4; ++ot)
            yac[j2][ot] = __builtin_amdgcn_mfma_f32_16x16x32_bf16(
                xa[j2], tb[ot], yac[j2][ot], 0, 0, 0);
      }
      // D -> Bl: lane holds 4 consecutive j at fixed o -> one b64 per tile
#pragma unroll
      for (int j2 = 0; j2 < 2; ++j2) {
        const int jloc4 = yjh * 32 + j2 * 16 + quad * 4;
#pragma unroll
        for (int ot = 0; ot < 4; ++ot) {
          const int crow = ytt * 64 + ot * 16 + lr;
          ushort4 u;
          u.x = f2bf(yac[j2][ot][0]); u.y = f2bf(yac[j2][ot][1]);
          u.z = f2bf(yac[j2][ot][2]); u.w = f2bf(yac[j2][ot][3]);
          const int off =
              crow * 64 + (((jloc4 >> 3) ^ (crow & 7)) * 8) + (jloc4 & 7);
          *(ushort4*)&Bl[off] = u;
        }
      }
      __syncthreads();            // drains vmcnt (A landed) + lgkm (Bl valid)
      // main MFMA
#pragma unroll
      for (int ks = 0; ks < 2; ++ks) {
        const int pc = (p0 ^ (ks * 4)) * 8;
        bf16x8 a[4], bb[4];
#pragma unroll
        for (int mi = 0; mi < 4; ++mi)
          a[mi] = *(const bf16x8*)&Al[(wr * 64 + mi * 16 + lr) * 64 + pc];
#pragma unroll
        for (int ci = 0; ci < 4; ++ci)
          bb[ci] = *(const bf16x8*)&Bl[(wc * 64 + ci * 16 + lr) * 64 + pc];
#pragma unroll
        for (int mi = 0; mi < 4; ++mi)
#pragma unroll
          for (int ci = 0; ci < 4; ++ci)
            acc[mi][ci] = __builtin_amdgcn_mfma_f32_16x16x32_bf16(
                a[mi], bb[ci], acc[mi][ci], 0, 0, 0);
      }
    }
  }

  // epilogue: C/D layout col=lane&15 (->c), row=quad*4+reg (->i). ReLU fused.
#pragma unroll
  for (int mi = 0; mi < 4; ++mi) {
    const int i = ib + wr * 64 + mi * 16 + quad * 4;
#pragma unroll
    for (int ci = 0; ci < 4; ++ci) {
      const int c = cb + wc * 64 + ci * 16 + lr;
      const int t = c >> 6, o = c & 63;      // 16-aligned tile: single t
#pragma unroll
      for (int r = 0; r < 4; ++r) {
        if (i + r < N_) {
          const float v = acc[mi][ci][r];
          out[((size_t)(b * T_ + t) * N_ + (i + r)) * O_ + o] = v > 0.f ? v : 0.f;
        }
      }
    }
  }
}

// ---------------------------------------------------------------------------
extern "C" void kernel_launch(void* const* d_in, const int* in_sizes, int n_in,
                              void* d_out, int out_size, void* d_ws, size_t ws_size,
                              hipStream_t stream) {
  const float* x     = (const float*)d_in[0];
  const float* SAtt  = (const float*)d_in[1];
  const float* cheb  = (const float*)d_in[2];
  const float* Theta = (const float*)d_in[3];
  float* out = (float*)d_out;

  unsigned short* ASt = (unsigned short*)d_ws;                 // 100.7 MB

  k_build_as<<<dim3(16, 16, 2), 256, 0, stream>>>(SAtt, cheb, ASt);
  k_gemm<<<768, 256, 0, stream>>>(ASt, x, Theta, out);
}